// Round 6
// baseline (30900.186 us; speedup 1.0000x reference)
//
#include <hip/hip_runtime.h>
#include <hip/hip_cooperative_groups.h>
#include <cstdint>

namespace cg = cooperative_groups;

#define NB 1024
#define NS 128
#define NH 256

#define M_ENC 0
#define M_DEC0 1
#define M_DEC 2

typedef unsigned short ushort_t;
typedef unsigned char uchar_t;

struct Params {
  const float *x;
  const float *enc_W_hh, *enc_b_ih, *enc_b_hh;
  const float *dec_W_hh, *dec_b_ih, *dec_b_hh;
  const float *g_Wk_w, *g_Wk_b, *p_Wk_w, *p_Wk_b;
  const float *gWT, *pWT, *gqb, *pqb;
  const float *gvw, *gvb, *pvw, *pvb;
  float *hb;      // 4 contiguous [NB*NH] buffers
  float *cbuf;
  ushort_t *gkh; uchar_t *gk8; ushort_t *gkn;
  ushort_t *pkh; uchar_t *pk8; ushort_t *pkn;
  int *mask; int *chosen;
  const float *F_enc, *F_dec, *d0proj;
  const uint2 *skeys;
  float *out;
};

__device__ __forceinline__ void tf2x32(uint32_t k0, uint32_t k1, uint32_t x0, uint32_t x1,
                                       uint32_t &o0, uint32_t &o1) {
  const uint32_t ks2 = k0 ^ k1 ^ 0x1BD11BDAu;
#define TF_R(r) { x0 += x1; x1 = (x1 << (r)) | (x1 >> (32 - (r))); x1 ^= x0; }
  x0 += k0; x1 += k1;
  TF_R(13) TF_R(15) TF_R(26) TF_R(6)
  x0 += k1; x1 += ks2 + 1u;
  TF_R(17) TF_R(29) TF_R(16) TF_R(24)
  x0 += ks2; x1 += k0 + 2u;
  TF_R(13) TF_R(15) TF_R(26) TF_R(6)
  x0 += k0; x1 += k1 + 3u;
  TF_R(17) TF_R(29) TF_R(16) TF_R(24)
  x0 += k1; x1 += ks2 + 4u;
  TF_R(13) TF_R(15) TF_R(26) TF_R(6)
  x0 += ks2; x1 += k0 + 5u;
#undef TF_R
  o0 = x0; o1 = x1;
}

__device__ __forceinline__ float fast_tanh(float x) {
  float ax = fabsf(x);
  float e = __expf(2.0f * ax);
  float r = 1.0f - 2.0f / (e + 1.0f);
  return copysignf(r, x);
}

__device__ __forceinline__ float sigm(float x) { return 1.0f / (1.0f + expf(-x)); }

// ---- 3.5-byte key codec: keep fp32 bits [31:4] with RTN. Arrays: hi16, lo8, nibble4 ----
__device__ __forceinline__ void pack28(float4 o, ushort4 &hi, uchar4 &l8, ushort_t &nib) {
  uint32_t a = __float_as_uint(o.x) + 8u;
  uint32_t b = __float_as_uint(o.y) + 8u;
  uint32_t c = __float_as_uint(o.z) + 8u;
  uint32_t d = __float_as_uint(o.w) + 8u;
  hi = make_ushort4((ushort_t)(a >> 16), (ushort_t)(b >> 16), (ushort_t)(c >> 16), (ushort_t)(d >> 16));
  l8 = make_uchar4((uchar_t)(a >> 8), (uchar_t)(b >> 8), (uchar_t)(c >> 8), (uchar_t)(d >> 8));
  nib = (ushort_t)(((a >> 4) & 0xFu) | (((b >> 4) & 0xFu) << 4) |
                   (((c >> 4) & 0xFu) << 8) | (((d >> 4) & 0xFu) << 12));
}

__device__ __forceinline__ float4 key_load(const ushort_t* __restrict__ kh,
                                           const uchar_t* __restrict__ k8,
                                           const ushort_t* __restrict__ kn,
                                           size_t row, int h0) {
  ushort4 hv = *(const ushort4*)(kh + row * 256 + h0);
  uchar4 lv = *(const uchar4*)(k8 + row * 256 + h0);
  uint32_t nv = kn[row * 64 + (h0 >> 2)];
  float4 r;
  r.x = __uint_as_float(((uint32_t)hv.x << 16) | ((uint32_t)lv.x << 8) | ((nv & 0xFu) << 4));
  r.y = __uint_as_float(((uint32_t)hv.y << 16) | ((uint32_t)lv.y << 8) | (((nv >> 4) & 0xFu) << 4));
  r.z = __uint_as_float(((uint32_t)hv.z << 16) | ((uint32_t)lv.z << 8) | (((nv >> 8) & 0xFu) << 4));
  r.w = __uint_as_float(((uint32_t)hv.w << 16) | ((uint32_t)lv.w << 8) | (((nv >> 12) & 0xFu) << 4));
  return r;
}

// ---------------- prep: fold emb_W through input weights; threefry split keys ----------------
__global__ __launch_bounds__(256) void prep_kernel(
    const float* __restrict__ emb_W, const float* __restrict__ enc_W_ih,
    const float* __restrict__ dec_W_ih, const float* __restrict__ dec_start,
    float* __restrict__ F_enc, float* __restrict__ F_dec,
    float* __restrict__ d0proj, uint2* __restrict__ skeys) {
  int j = blockIdx.x * 256 + threadIdx.x;  // 0..1023
  const float* er = enc_W_ih + j * 256;
  const float* dr = dec_W_ih + j * 256;
  float fe0 = 0.f, fe1 = 0.f, fd0 = 0.f, fd1 = 0.f, dp = 0.f;
  for (int e = 0; e < 256; ++e) {
    float we0 = emb_W[e], we1 = emb_W[256 + e];
    float ev = er[e], dv = dr[e];
    fe0 = fmaf(we0, ev, fe0); fe1 = fmaf(we1, ev, fe1);
    fd0 = fmaf(we0, dv, fd0); fd1 = fmaf(we1, dv, fd1);
    dp = fmaf(dec_start[e], dv, dp);
  }
  F_enc[j] = fe0; F_enc[1024 + j] = fe1;
  F_dec[j] = fd0; F_dec[1024 + j] = fd1;
  d0proj[j] = dp;
  if (blockIdx.x == 0 && threadIdx.x < NS) {
    uint32_t o0, o1;
    tf2x32(0u, 42u, 0u, (uint32_t)threadIdx.x, o0, o1);
    skeys[threadIdx.x] = make_uint2(o0, o1);
  }
}

__global__ __launch_bounds__(256) void transpose_qw(
    const float* __restrict__ gW, const float* __restrict__ pW,
    float* __restrict__ gWT, float* __restrict__ pWT) {
  int k = blockIdx.x, j = threadIdx.x;
  gWT[k * 256 + j] = gW[j * 256 + k];
  pWT[k * 256 + j] = pW[j * 256 + k];
}

__global__ void diag_fill(float* out, float v, int n) {
  int i = blockIdx.x * blockDim.x + threadIdx.x;
  if (i < n) out[i] = v;
}

// ---------------- LSTM tile: threads 0..511 active, round-5 bit-identical ----------------
template <int MODE>
__device__ __forceinline__ void lstm_step(const Params& P, const float* __restrict__ A,
    const float* __restrict__ B0, const float* __restrict__ bias0,
    const float* __restrict__ bias1, float* __restrict__ out0, float* __restrict__ out1,
    const float* __restrict__ F, int t, float* smem) {
  const int tid = threadIdx.x;
  const bool act = tid < 512;
  const int bx = blockIdx.x & 15, by = blockIdx.x >> 4;
  const int m0 = bx * 64;
  float* As = smem;
  float* Bs = smem + 32 * 68;
  const int tx = tid & 15;
  const int ty = (tid >> 4) & 31;
  const int nl = (tid >> 3) & 63;
  const int c4 = (tid & 7) * 4;

  const float* brow = B0;
  const float* ap = A;
  if (act) {
    const int j = ((nl >> 4) << 8) + (by << 4) + (nl & 15);
    brow = B0 + (size_t)j * 256 + c4;
    ap = A + (size_t)(m0 + nl) * 256 + c4;
  }
  float acc[2][4] = {{0.f, 0.f, 0.f, 0.f}, {0.f, 0.f, 0.f, 0.f}};
  for (int k0 = 0; k0 < 256; k0 += 32) {
    float4 a0 = make_float4(0.f, 0.f, 0.f, 0.f), b0 = a0;
    if (act) {
      a0 = *(const float4*)(ap + k0);
      b0 = *(const float4*)(brow + k0);
    }
    __syncthreads();
    if (act) {
      As[(c4 + 0) * 68 + nl] = a0.x; As[(c4 + 1) * 68 + nl] = a0.y;
      As[(c4 + 2) * 68 + nl] = a0.z; As[(c4 + 3) * 68 + nl] = a0.w;
      Bs[(c4 + 0) * 68 + nl] = b0.x; Bs[(c4 + 1) * 68 + nl] = b0.y;
      Bs[(c4 + 2) * 68 + nl] = b0.z; Bs[(c4 + 3) * 68 + nl] = b0.w;
    }
    __syncthreads();
    if (act) {
#pragma unroll
      for (int kk = 0; kk < 32; ++kk) {
        float2 av = *(const float2*)(As + kk * 68 + ty * 2);
        float4 bv = *(const float4*)(Bs + kk * 68 + tx * 4);
        acc[0][0] = fmaf(av.x, bv.x, acc[0][0]);
        acc[0][1] = fmaf(av.x, bv.y, acc[0][1]);
        acc[0][2] = fmaf(av.x, bv.z, acc[0][2]);
        acc[0][3] = fmaf(av.x, bv.w, acc[0][3]);
        acc[1][0] = fmaf(av.y, bv.x, acc[1][0]);
        acc[1][1] = fmaf(av.y, bv.y, acc[1][1]);
        acc[1][2] = fmaf(av.y, bv.z, acc[1][2]);
        acc[1][3] = fmaf(av.y, bv.w, acc[1][3]);
      }
    }
  }
  float bsum[4], fa[4], fb[4];
  float xv0[2] = {0.f, 0.f}, xv1[2] = {0.f, 0.f};
  if (act) {
#pragma unroll
    for (int c = 0; c < 4; ++c) {
      int n = tx * 4 + c;
      int jx = ((n >> 4) << 8) + (by << 4) + (n & 15);
      bsum[c] = bias0[jx] + bias1[jx];
      fa[c] = F[jx];
      if constexpr (MODE != M_DEC0) fb[c] = F[1024 + jx]; else fb[c] = 0.0f;
    }
    if constexpr (MODE == M_ENC) {
#pragma unroll
      for (int r = 0; r < 2; ++r) {
        int m = m0 + ty * 2 + r;
        xv0[r] = P.x[m * (NS * 2) + t * 2 + 0];
        xv1[r] = P.x[m * (NS * 2) + t * 2 + 1];
      }
    } else if constexpr (MODE == M_DEC) {
#pragma unroll
      for (int r = 0; r < 2; ++r) {
        int m = m0 + ty * 2 + r;
        int cs = P.chosen[m];
        xv0[r] = P.x[m * (NS * 2) + cs * 2 + 0];
        xv1[r] = P.x[m * (NS * 2) + cs * 2 + 1];
      }
    }
  }
  __syncthreads();
  float* Cs = smem;
  if (act) {
#pragma unroll
    for (int r = 0; r < 2; ++r) {
#pragma unroll
      for (int c = 0; c < 4; ++c) {
        float v = acc[r][c] + bsum[c];
        if constexpr (MODE == M_DEC0) v += fa[c];
        else v += xv0[r] * fa[c] + xv1[r] * fb[c];
        Cs[(ty * 2 + r) * 68 + tx * 4 + c] = v;
      }
    }
  }
  __syncthreads();
  if (act) {
    const int b_l = tid >> 3;
    const int h2 = (tid & 7) * 2;
    const float* crow = Cs + b_l * 68;
    float2 gi = *(const float2*)(crow + h2);
    float2 gf = *(const float2*)(crow + 16 + h2);
    float2 gg = *(const float2*)(crow + 32 + h2);
    float2 go = *(const float2*)(crow + 48 + h2);
    size_t base = (size_t)(m0 + b_l) * 256 + (by << 4) + h2;
    float2 cp = *(const float2*)(out1 + base);
    float2 cn, hn;
    cn.x = sigm(gf.x) * cp.x + sigm(gi.x) * tanhf(gg.x); hn.x = sigm(go.x) * tanhf(cn.x);
    cn.y = sigm(gf.y) * cp.y + sigm(gi.y) * tanhf(gg.y); hn.y = sigm(go.y) * tanhf(cn.y);
    *(float2*)(out1 + base) = cn;
    *(float2*)(out0 + base) = hn;
  }
}

// ---------------- keys tile (one of 512), threads 0..511 active, round-5 bit-identical ----------------
__device__ __forceinline__ void keys_tile(const Params& P, int T, int t0, float* smem) {
  const int tid = threadIdx.x;
  const bool act = tid < 512;
  const int bx = T & 15, cy = (T >> 4) & 7, zz = T >> 7;
  const int t = t0 + zz;
  const float* A = P.hb + (size_t)zz * NB * NH;
  const int m0 = bx * 64;
  float* As = smem;
  float* Bs = smem + 32 * 68;
  const int tx = tid & 15;
  const int ty = (tid >> 4) & 31;
  const int nl = (tid >> 3) & 63;
  const int c4 = (tid & 7) * 4;

  const float* brow = P.g_Wk_w;
  const float* ap = A;
  if (act) {
    const int j = cy * 64 + nl;   // 0..511
    brow = ((j < 256) ? (P.g_Wk_w + (size_t)j * 256)
                      : (P.p_Wk_w + (size_t)(j - 256) * 256)) + c4;
    ap = A + (size_t)(m0 + nl) * 256 + c4;
  }
  float acc[2][4] = {{0.f, 0.f, 0.f, 0.f}, {0.f, 0.f, 0.f, 0.f}};
  for (int k0 = 0; k0 < 256; k0 += 32) {
    float4 a0 = make_float4(0.f, 0.f, 0.f, 0.f), b0 = a0;
    if (act) {
      a0 = *(const float4*)(ap + k0);
      b0 = *(const float4*)(brow + k0);
    }
    __syncthreads();
    if (act) {
      As[(c4 + 0) * 68 + nl] = a0.x; As[(c4 + 1) * 68 + nl] = a0.y;
      As[(c4 + 2) * 68 + nl] = a0.z; As[(c4 + 3) * 68 + nl] = a0.w;
      Bs[(c4 + 0) * 68 + nl] = b0.x; Bs[(c4 + 1) * 68 + nl] = b0.y;
      Bs[(c4 + 2) * 68 + nl] = b0.z; Bs[(c4 + 3) * 68 + nl] = b0.w;
    }
    __syncthreads();
    if (act) {
#pragma unroll
      for (int kk = 0; kk < 32; ++kk) {
        float2 av = *(const float2*)(As + kk * 68 + ty * 2);
        float4 bv = *(const float4*)(Bs + kk * 68 + tx * 4);
        acc[0][0] = fmaf(av.x, bv.x, acc[0][0]);
        acc[0][1] = fmaf(av.x, bv.y, acc[0][1]);
        acc[0][2] = fmaf(av.x, bv.z, acc[0][2]);
        acc[0][3] = fmaf(av.x, bv.w, acc[0][3]);
        acc[1][0] = fmaf(av.y, bv.x, acc[1][0]);
        acc[1][1] = fmaf(av.y, bv.y, acc[1][1]);
        acc[1][2] = fmaf(av.y, bv.z, acc[1][2]);
        acc[1][3] = fmaf(av.y, bv.w, acc[1][3]);
      }
    }
  }
  if (act) {
    const int nbase = cy * 64 + tx * 4;
    const bool isp = (nbase >= 256);
    const int n = isp ? (nbase - 256) : nbase;
    float4 b4 = *(const float4*)((isp ? P.p_Wk_b : P.g_Wk_b) + n);
    ushort_t* kh = isp ? P.pkh : P.gkh;
    uchar_t* k8 = isp ? P.pk8 : P.gk8;
    ushort_t* kn = isp ? P.pkn : P.gkn;
#pragma unroll
    for (int r = 0; r < 2; ++r) {
      int m = m0 + ty * 2 + r;
      float4 o;
      o.x = acc[r][0] + b4.x; o.y = acc[r][1] + b4.y;
      o.z = acc[r][2] + b4.z; o.w = acc[r][3] + b4.w;
      size_t row = (size_t)m * NS + t;
      ushort4 hi; uchar4 l8; ushort_t nib;
      pack28(o, hi, l8, nib);
      *(ushort4*)(kh + row * 256 + n) = hi;
      *(uchar4*)(k8 + row * 256 + n) = l8;
      kn[row * 64 + (n >> 2)] = nib;
    }
  }
}

// ---------------- the whole network: one cooperative persistent kernel ----------------
__global__ __launch_bounds__(1024) void net_kernel(Params P) {
  cg::grid_group grid = cg::this_grid();
  __shared__ float gsm[64 * 68];
  // attn shared state (4 batch rows per block)
  __shared__ float hs[4][256], qs[4][256], vsm[4][256], qq[4][256];
  __shared__ float part[4][4][256];
  __shared__ float wm[4][4], wl[4][4];
  __shared__ float lgs[4][NS], sv[4][NS];
  __shared__ int msk[4][NS];
  __shared__ float red_lse[4];
  __shared__ int ich[4];

  float* hb[4] = {P.hb, P.hb + NB * NH, P.hb + 2 * NB * NH, P.hb + 3 * NB * NH};

  // ---- encoder ----
  for (int t = 0; t < NS; ++t) {
    const float* hin = (t == 0) ? hb[3] : hb[(t - 1) & 3];
    lstm_step<M_ENC>(P, hin, P.enc_W_hh, P.enc_b_ih, P.enc_b_hh,
                     hb[t & 3], P.cbuf, P.F_enc, t, gsm);
    grid.sync();
    if ((t & 3) == 3) {
      keys_tile(P, blockIdx.x * 2 + 0, t - 3, gsm);
      keys_tile(P, blockIdx.x * 2 + 1, t - 3, gsm);
      grid.sync();
    }
  }

  // ---- decoder ----
  for (int t = 0; t < NS; ++t) {
    const float* hin = (t == 0) ? hb[3] : hb[(t - 1) & 3];
    if (t == 0)
      lstm_step<M_DEC0>(P, hin, P.dec_W_hh, P.dec_b_ih, P.dec_b_hh,
                        hb[0], P.cbuf, P.d0proj, t, gsm);
    else
      lstm_step<M_DEC>(P, hin, P.dec_W_hh, P.dec_b_ih, P.dec_b_hh,
                       hb[t & 3], P.cbuf, P.F_dec, t, gsm);
    grid.sync();

    // ---- fused attention + sample (verbatim round-5 attn body) ----
    {
      const float* h = hb[t & 3];
      const int tid = threadIdx.x;
      const int grp = tid >> 8;
      const int gt = tid & 255;
      const int b = blockIdx.x * 4 + grp;
      const int wv = gt >> 6, lane = gt & 63;
      const int h0 = lane * 4;

      hs[grp][gt] = h[b * 256 + gt];
      vsm[grp][gt] = P.gvw[gt];
      if (gt < NS) msk[grp][gt] = P.mask[b * NS + gt];
      __syncthreads();

      // phase 1: qg = g_Wq . h + b
      {
        float a = P.gqb[gt];
        const float* wc = P.gWT + gt;
#pragma unroll 8
        for (int k = 0; k < 256; ++k) a = fmaf(wc[k * 256], hs[grp][k], a);
        qs[grp][gt] = a;
      }
      __syncthreads();

      // phase 2: glimpse online-softmax attention
      {
        const float vbias = P.gvb[0];
        float q0 = qs[grp][h0], q1 = qs[grp][h0 + 1], q2 = qs[grp][h0 + 2], q3 = qs[grp][h0 + 3];
        float v0 = vsm[grp][h0], v1 = vsm[grp][h0 + 1], v2 = vsm[grp][h0 + 2], v3 = vsm[grp][h0 + 3];
        float m = -INFINITY, l = 0.f;
        float4 acc = make_float4(0.f, 0.f, 0.f, 0.f);
#pragma unroll 2
        for (int si = 0; si < 32; ++si) {
          int s = wv * 32 + si;
          size_t row = (size_t)b * NS + s;
          float4 kv = key_load(P.gkh, P.gk8, P.gkn, row, h0);
          float p = fast_tanh(q0 + kv.x) * v0 + fast_tanh(q1 + kv.y) * v1 +
                    fast_tanh(q2 + kv.z) * v2 + fast_tanh(q3 + kv.w) * v3;
#pragma unroll
          for (int off = 32; off; off >>= 1) p += __shfl_xor(p, off);
          if (!msk[grp][s]) {
            float lg = 10.0f * tanhf(p + vbias);
            float mn = fmaxf(m, lg);
            float scale = (m == -INFINITY) ? 0.0f : expf(m - mn);
            float pe = expf(lg - mn);
            acc.x = fmaf(acc.x, scale, pe * kv.x);
            acc.y = fmaf(acc.y, scale, pe * kv.y);
            acc.z = fmaf(acc.z, scale, pe * kv.z);
            acc.w = fmaf(acc.w, scale, pe * kv.w);
            l = l * scale + pe;
            m = mn;
          }
        }
        *(float4*)&part[grp][wv][h0] = acc;
        if (lane == 0) { wm[grp][wv] = m; wl[grp][wv] = l; }
      }
      __syncthreads();
      {
        float mg = fmaxf(fmaxf(wm[grp][0], wm[grp][1]), fmaxf(wm[grp][2], wm[grp][3]));
        float w0 = (wm[grp][0] == -INFINITY) ? 0.f : expf(wm[grp][0] - mg);
        float w1 = (wm[grp][1] == -INFINITY) ? 0.f : expf(wm[grp][1] - mg);
        float w2 = (wm[grp][2] == -INFINITY) ? 0.f : expf(wm[grp][2] - mg);
        float w3 = (wm[grp][3] == -INFINITY) ? 0.f : expf(wm[grp][3] - mg);
        float denom = w0 * wl[grp][0] + w1 * wl[grp][1] + w2 * wl[grp][2] + w3 * wl[grp][3];
        float num = w0 * part[grp][0][gt] + w1 * part[grp][1][gt] +
                    w2 * part[grp][2][gt] + w3 * part[grp][3][gt];
        qq[grp][gt] = num / denom;
        vsm[grp][gt] = P.pvw[gt];
      }
      __syncthreads();

      // phase 3: qp = p_Wq . query + b
      {
        float a = P.pqb[gt];
        const float* wc = P.pWT + gt;
#pragma unroll 8
        for (int k = 0; k < 256; ++k) a = fmaf(wc[k * 256], qq[grp][k], a);
        qs[grp][gt] = a;
      }
      __syncthreads();

      // phase 4: pointer logits
      {
        const float vbias = P.pvb[0];
        float q0 = qs[grp][h0], q1 = qs[grp][h0 + 1], q2 = qs[grp][h0 + 2], q3 = qs[grp][h0 + 3];
        float v0 = vsm[grp][h0], v1 = vsm[grp][h0 + 1], v2 = vsm[grp][h0 + 2], v3 = vsm[grp][h0 + 3];
#pragma unroll 2
        for (int si = 0; si < 32; ++si) {
          int s = wv * 32 + si;
          size_t row = (size_t)b * NS + s;
          float4 kv = key_load(P.pkh, P.pk8, P.pkn, row, h0);
          float p = fast_tanh(q0 + kv.x) * v0 + fast_tanh(q1 + kv.y) * v1 +
                    fast_tanh(q2 + kv.z) * v2 + fast_tanh(q3 + kv.w) * v3;
#pragma unroll
          for (int off = 32; off; off >>= 1) p += __shfl_down(p, off);
          if (lane == 0) {
            float lv = 10.0f * tanhf(p + vbias);
            lgs[grp][s] = msk[grp][s] ? -100000.0f : lv;
          }
        }
      }
      __syncthreads();
      if (wv == 0) {
        float a0 = lgs[grp][lane], a1 = lgs[grp][lane + 64];
        float m = fmaxf(a0, a1);
#pragma unroll
        for (int off = 32; off; off >>= 1) m = fmaxf(m, __shfl_xor(m, off));
        float e0 = expf(a0 - m), e1 = expf(a1 - m);
        float sum = e0 + e1;
#pragma unroll
        for (int off = 32; off; off >>= 1) sum += __shfl_xor(sum, off);
        if (lane == 0) red_lse[grp] = m + logf(sum);
      }
      __syncthreads();
      if (gt < NS) {
        uint32_t i = (uint32_t)(b * NS + gt);
        uint2 sk = P.skeys[t];
        uint32_t o0, o1;
        tf2x32(sk.x, sk.y, 0u, i, o0, o1);
        uint32_t bits = o0 ^ o1;
        float u = __uint_as_float((bits >> 9) | 0x3f800000u) - 1.0f;
        u = u + 1.17549435e-38f;
        u = fmaxf(u, 1.17549435e-38f);
        float g = -logf(-logf(u));
        sv[grp][gt] = lgs[grp][gt] + g;
      }
      __syncthreads();
      if (wv == 0) {
        float bv = sv[grp][lane]; int bi = lane;
        float ov0 = sv[grp][lane + 64];
        if (ov0 > bv) { bv = ov0; bi = lane + 64; }
#pragma unroll
        for (int off = 32; off; off >>= 1) {
          float ov = __shfl_down(bv, off);
          int oi = __shfl_down(bi, off);
          if (ov > bv) { bv = ov; bi = oi; }
        }
        if (lane == 0) ich[grp] = bi;
      }
      __syncthreads();
      if (gt == 0) {
        int cs = ich[grp];
        P.out[b * NS + t] = lgs[grp][cs] - red_lse[grp];
        P.out[NB * NS + b * NS + t] = (float)cs;
        P.mask[b * NS + cs] = 1;
        P.chosen[b] = cs;
      }
    }
    grid.sync();
  }
}

extern "C" void kernel_launch(void* const* d_in, const int* in_sizes, int n_in,
                              void* d_out, int out_size, void* d_ws, size_t ws_size,
                              hipStream_t stream) {
  const float* x        = (const float*)d_in[0];
  const float* emb_W    = (const float*)d_in[1];
  const float* enc_W_ih = (const float*)d_in[2];
  const float* enc_W_hh = (const float*)d_in[3];
  const float* enc_b_ih = (const float*)d_in[4];
  const float* enc_b_hh = (const float*)d_in[5];
  const float* dec_W_ih = (const float*)d_in[6];
  const float* dec_W_hh = (const float*)d_in[7];
  const float* dec_b_ih = (const float*)d_in[8];
  const float* dec_b_hh = (const float*)d_in[9];
  const float* g_Wq_w = (const float*)d_in[10];
  const float* g_Wq_b = (const float*)d_in[11];
  const float* g_Wk_w = (const float*)d_in[12];
  const float* g_Wk_b = (const float*)d_in[13];
  const float* g_v_w  = (const float*)d_in[14];
  const float* g_v_b  = (const float*)d_in[15];
  const float* p_Wq_w = (const float*)d_in[16];
  const float* p_Wq_b = (const float*)d_in[17];
  const float* p_Wk_w = (const float*)d_in[18];
  const float* p_Wk_b = (const float*)d_in[19];
  const float* p_v_w  = (const float*)d_in[20];
  const float* p_v_b  = (const float*)d_in[21];
  const float* dec_start = (const float*)d_in[22];
  (void)in_sizes; (void)n_in;

  const size_t KELEM = (size_t)NB * NS * NH;
  char* w = (char*)d_ws;
  size_t off = 0;
  auto alloc = [&](size_t bytes) -> void* {
    void* p = w + off;
    off += (bytes + 255) & ~(size_t)255;
    return p;
  };
  ushort_t* gkh = (ushort_t*)alloc(KELEM * 2);
  uchar_t*  gk8 = (uchar_t*)alloc(KELEM);
  ushort_t* gkn = (ushort_t*)alloc(KELEM / 2);
  ushort_t* pkh = (ushort_t*)alloc(KELEM * 2);
  uchar_t*  pk8 = (uchar_t*)alloc(KELEM);
  ushort_t* pkn = (ushort_t*)alloc(KELEM / 2);

  float* hbase  = (float*)alloc((size_t)4 * NB * NH * 4);   // 4 contiguous h buffers
  float* cbuf   = (float*)alloc((size_t)NB * NH * 4);
  int*   mask   = (int*)alloc((size_t)NB * NS * 4);
  int*   chosen = (int*)alloc((size_t)NB * 4);
  float* F_enc  = (float*)alloc(2048 * 4);
  float* F_dec  = (float*)alloc(2048 * 4);
  float* d0proj = (float*)alloc(1024 * 4);
  uint2* skeys  = (uint2*)alloc(NS * 8);
  float* gWT    = (float*)alloc(256 * 256 * 4);
  float* pWT    = (float*)alloc(256 * 256 * 4);

  if (off > ws_size) {
    diag_fill<<<(out_size + 255) / 256, 256, 0, stream>>>((float*)d_out, (float)ws_size, out_size);
    return;
  }

  hipMemsetAsync(hbase + 3 * NB * NH, 0, (size_t)NB * NH * 4, stream);  // h_in for enc t=0
  hipMemsetAsync(cbuf, 0, (size_t)NB * NH * 4, stream);
  hipMemsetAsync(mask, 0, (size_t)NB * NS * 4, stream);
  prep_kernel<<<4, 256, 0, stream>>>(emb_W, enc_W_ih, dec_W_ih, dec_start,
                                     F_enc, F_dec, d0proj, skeys);
  transpose_qw<<<256, 256, 0, stream>>>(g_Wq_w, p_Wq_w, gWT, pWT);

  Params P;
  P.x = x;
  P.enc_W_hh = enc_W_hh; P.enc_b_ih = enc_b_ih; P.enc_b_hh = enc_b_hh;
  P.dec_W_hh = dec_W_hh; P.dec_b_ih = dec_b_ih; P.dec_b_hh = dec_b_hh;
  P.g_Wk_w = g_Wk_w; P.g_Wk_b = g_Wk_b; P.p_Wk_w = p_Wk_w; P.p_Wk_b = p_Wk_b;
  P.gWT = gWT; P.pWT = pWT; P.gqb = g_Wq_b; P.pqb = p_Wq_b;
  P.gvw = g_v_w; P.gvb = g_v_b; P.pvw = p_v_w; P.pvb = p_v_b;
  P.hb = hbase; P.cbuf = cbuf;
  P.gkh = gkh; P.gk8 = gk8; P.gkn = gkn;
  P.pkh = pkh; P.pk8 = pk8; P.pkn = pkn;
  P.mask = mask; P.chosen = chosen;
  P.F_enc = F_enc; P.F_dec = F_dec; P.d0proj = d0proj;
  P.skeys = skeys;
  P.out = (float*)d_out;

  void* kargs[] = {(void*)&P};
  hipLaunchCooperativeKernel((void*)net_kernel, dim3(256), dim3(1024), kargs, 0, stream);
}

// Round 7
// 13910.170 us; speedup vs baseline: 2.2214x; 2.2214x over previous
//
#include <hip/hip_runtime.h>
#include <cstdint>

#define NB 1024
#define NS 128
#define NE 256
#define NH 256

#define M_ENC 0
#define M_DEC0 1
#define M_DEC 2

typedef unsigned short ushort_t;
typedef unsigned char uchar_t;

__device__ __forceinline__ void tf2x32(uint32_t k0, uint32_t k1, uint32_t x0, uint32_t x1,
                                       uint32_t &o0, uint32_t &o1) {
  const uint32_t ks2 = k0 ^ k1 ^ 0x1BD11BDAu;
#define TF_R(r) { x0 += x1; x1 = (x1 << (r)) | (x1 >> (32 - (r))); x1 ^= x0; }
  x0 += k0; x1 += k1;
  TF_R(13) TF_R(15) TF_R(26) TF_R(6)
  x0 += k1; x1 += ks2 + 1u;
  TF_R(17) TF_R(29) TF_R(16) TF_R(24)
  x0 += ks2; x1 += k0 + 2u;
  TF_R(13) TF_R(15) TF_R(26) TF_R(6)
  x0 += k0; x1 += k1 + 3u;
  TF_R(17) TF_R(29) TF_R(16) TF_R(24)
  x0 += k1; x1 += ks2 + 4u;
  TF_R(13) TF_R(15) TF_R(26) TF_R(6)
  x0 += ks2; x1 += k0 + 5u;
#undef TF_R
  o0 = x0; o1 = x1;
}

__device__ __forceinline__ float fast_tanh(float x) {
  float ax = fabsf(x);
  float e = __expf(2.0f * ax);
  float r = 1.0f - 2.0f / (e + 1.0f);
  return copysignf(r, x);
}

__device__ __forceinline__ float sigm(float x) { return 1.0f / (1.0f + expf(-x)); }

// ---- 3.5-byte key codec: keep fp32 bits [31:4] with RTN. Arrays: hi16, lo8, nibble4 ----
__device__ __forceinline__ void pack28(float4 o, ushort4 &hi, uchar4 &l8, ushort_t &nib) {
  uint32_t a = __float_as_uint(o.x) + 8u;
  uint32_t b = __float_as_uint(o.y) + 8u;
  uint32_t c = __float_as_uint(o.z) + 8u;
  uint32_t d = __float_as_uint(o.w) + 8u;
  hi = make_ushort4((ushort_t)(a >> 16), (ushort_t)(b >> 16), (ushort_t)(c >> 16), (ushort_t)(d >> 16));
  l8 = make_uchar4((uchar_t)(a >> 8), (uchar_t)(b >> 8), (uchar_t)(c >> 8), (uchar_t)(d >> 8));
  nib = (ushort_t)(((a >> 4) & 0xFu) | (((b >> 4) & 0xFu) << 4) |
                   (((c >> 4) & 0xFu) << 8) | (((d >> 4) & 0xFu) << 12));
}

__device__ __forceinline__ float4 key_load(const ushort_t* __restrict__ kh,
                                           const uchar_t* __restrict__ k8,
                                           const ushort_t* __restrict__ kn,
                                           size_t row, int h0) {
  ushort4 hv = *(const ushort4*)(kh + row * 256 + h0);
  uchar4 lv = *(const uchar4*)(k8 + row * 256 + h0);
  uint32_t nv = kn[row * 64 + (h0 >> 2)];
  float4 r;
  r.x = __uint_as_float(((uint32_t)hv.x << 16) | ((uint32_t)lv.x << 8) | ((nv & 0xFu) << 4));
  r.y = __uint_as_float(((uint32_t)hv.y << 16) | ((uint32_t)lv.y << 8) | (((nv >> 4) & 0xFu) << 4));
  r.z = __uint_as_float(((uint32_t)hv.z << 16) | ((uint32_t)lv.z << 8) | (((nv >> 8) & 0xFu) << 4));
  r.w = __uint_as_float(((uint32_t)hv.w << 16) | ((uint32_t)lv.w << 8) | (((nv >> 12) & 0xFu) << 4));
  return r;
}

// ---------------- prep: fold emb_W through input weights; threefry split keys ----------------
__global__ __launch_bounds__(256) void prep_kernel(
    const float* __restrict__ emb_W, const float* __restrict__ enc_W_ih,
    const float* __restrict__ dec_W_ih, const float* __restrict__ dec_start,
    float* __restrict__ F_enc, float* __restrict__ F_dec,
    float* __restrict__ d0proj, uint2* __restrict__ skeys) {
  int j = blockIdx.x * 256 + threadIdx.x;  // 0..1023
  const float* er = enc_W_ih + j * 256;
  const float* dr = dec_W_ih + j * 256;
  float fe0 = 0.f, fe1 = 0.f, fd0 = 0.f, fd1 = 0.f, dp = 0.f;
  for (int e = 0; e < 256; ++e) {
    float we0 = emb_W[e], we1 = emb_W[256 + e];
    float ev = er[e], dv = dr[e];
    fe0 = fmaf(we0, ev, fe0); fe1 = fmaf(we1, ev, fe1);
    fd0 = fmaf(we0, dv, fd0); fd1 = fmaf(we1, dv, fd1);
    dp = fmaf(dec_start[e], dv, dp);
  }
  F_enc[j] = fe0; F_enc[1024 + j] = fe1;
  F_dec[j] = fd0; F_dec[1024 + j] = fd1;
  d0proj[j] = dp;
  if (blockIdx.x == 0 && threadIdx.x < NS) {
    uint32_t o0, o1;
    tf2x32(0u, 42u, 0u, (uint32_t)threadIdx.x, o0, o1);
    skeys[threadIdx.x] = make_uint2(o0, o1);
  }
}

// transpose the two query-projection weights: WT[k][j] = W[j][k]
__global__ __launch_bounds__(256) void transpose_qw(
    const float* __restrict__ gW, const float* __restrict__ pW,
    float* __restrict__ gWT, float* __restrict__ pWT) {
  int k = blockIdx.x, j = threadIdx.x;
  gWT[k * 256 + j] = gW[j * 256 + k];
  pWT[k * 256 + j] = pW[j * 256 + k];
}

__global__ void diag_fill(float* out, float v, int n) {
  int i = blockIdx.x * blockDim.x + threadIdx.x;
  if (i < n) out[i] = v;
}

// ---------------- GEMM macro body: 512 threads, 64x64 tile, K=256, acc[2][4] ----------------
#define GEMM_LOAD_COMPUTE()                                                         \
  float acc[2][4];                                                                  \
  _Pragma("unroll") for (int i = 0; i < 2; ++i)                                     \
      _Pragma("unroll") for (int jj = 0; jj < 4; ++jj) acc[i][jj] = 0.0f;           \
  for (int k0 = 0; k0 < 256; k0 += 32) {                                            \
    float4 a0 = *(const float4*)(ap + k0);                                          \
    float4 b0 = *(const float4*)(brow + k0);                                        \
    __syncthreads();                                                                \
    As[(c4 + 0) * 68 + nl] = a0.x; As[(c4 + 1) * 68 + nl] = a0.y;                   \
    As[(c4 + 2) * 68 + nl] = a0.z; As[(c4 + 3) * 68 + nl] = a0.w;                   \
    Bs[(c4 + 0) * 68 + nl] = b0.x; Bs[(c4 + 1) * 68 + nl] = b0.y;                   \
    Bs[(c4 + 2) * 68 + nl] = b0.z; Bs[(c4 + 3) * 68 + nl] = b0.w;                   \
    __syncthreads();                                                                \
    _Pragma("unroll") for (int kk = 0; kk < 32; ++kk) {                             \
      float2 av = *(const float2*)(As + kk * 68 + ty * 2);                          \
      float4 bv = *(const float4*)(Bs + kk * 68 + tx * 4);                          \
      acc[0][0] = fmaf(av.x, bv.x, acc[0][0]);                                      \
      acc[0][1] = fmaf(av.x, bv.y, acc[0][1]);                                      \
      acc[0][2] = fmaf(av.x, bv.z, acc[0][2]);                                      \
      acc[0][3] = fmaf(av.x, bv.w, acc[0][3]);                                      \
      acc[1][0] = fmaf(av.y, bv.x, acc[1][0]);                                      \
      acc[1][1] = fmaf(av.y, bv.y, acc[1][1]);                                      \
      acc[1][2] = fmaf(av.y, bv.z, acc[1][2]);                                      \
      acc[1][3] = fmaf(av.y, bv.w, acc[1][3]);                                      \
    }                                                                               \
  }

// ---------------- LSTM GEMM (+ cell epilogue) ----------------
template <int MODE>
__global__ __launch_bounds__(512) void gemm_kernel(
    const float* __restrict__ A, const float* __restrict__ B0,
    const float* __restrict__ bias0, const float* __restrict__ bias1,
    float* __restrict__ out0, float* __restrict__ out1,
    const float* __restrict__ x, const float* __restrict__ F,
    const int* __restrict__ chosen, int t) {
  __shared__ float smem[64 * 68];
  float* As = smem;
  float* Bs = smem + 32 * 68;
  const int tid = threadIdx.x;
  const int tx = tid & 15;
  const int ty = tid >> 4;
  const int m0 = blockIdx.x * 64;
  const int nl = tid >> 3;
  const int c4 = (tid & 7) * 4;

  const int j = ((nl >> 4) << 8) + (blockIdx.y << 4) + (nl & 15);
  const float* brow = B0 + (size_t)j * 256 + c4;
  const float* ap = A + (size_t)(m0 + nl) * 256 + c4;

  GEMM_LOAD_COMPUTE()

  float bsum[4], fa[4], fb[4];
#pragma unroll
  for (int c = 0; c < 4; ++c) {
    int n = tx * 4 + c;
    int jx = ((n >> 4) << 8) + (blockIdx.y << 4) + (n & 15);
    bsum[c] = bias0[jx] + bias1[jx];
    fa[c] = F[jx];
    if constexpr (MODE != M_DEC0) fb[c] = F[1024 + jx]; else fb[c] = 0.0f;
  }
  float xv0[2] = {0, 0}, xv1[2] = {0, 0};
  if constexpr (MODE == M_ENC) {
#pragma unroll
    for (int r = 0; r < 2; ++r) {
      int m = m0 + ty * 2 + r;
      xv0[r] = x[m * (NS * 2) + t * 2 + 0];
      xv1[r] = x[m * (NS * 2) + t * 2 + 1];
    }
  } else if constexpr (MODE == M_DEC) {
#pragma unroll
    for (int r = 0; r < 2; ++r) {
      int m = m0 + ty * 2 + r;
      int cs = chosen[m];
      xv0[r] = x[m * (NS * 2) + cs * 2 + 0];
      xv1[r] = x[m * (NS * 2) + cs * 2 + 1];
    }
  }
  __syncthreads();
  float* Cs = smem;  // [64][68]
#pragma unroll
  for (int r = 0; r < 2; ++r) {
#pragma unroll
    for (int c = 0; c < 4; ++c) {
      float v = acc[r][c] + bsum[c];
      if constexpr (MODE == M_DEC0) v += fa[c];
      else v += xv0[r] * fa[c] + xv1[r] * fb[c];
      Cs[(ty * 2 + r) * 68 + tx * 4 + c] = v;
    }
  }
  __syncthreads();
  const int b_l = tid >> 3;
  const int h2 = (tid & 7) * 2;
  const float* crow = Cs + b_l * 68;
  float2 gi = *(const float2*)(crow + h2);
  float2 gf = *(const float2*)(crow + 16 + h2);
  float2 gg = *(const float2*)(crow + 32 + h2);
  float2 go = *(const float2*)(crow + 48 + h2);
  size_t base = (size_t)(m0 + b_l) * 256 + (blockIdx.y << 4) + h2;
  float2 cp = *(const float2*)(out1 + base);
  float2 cn, hn;
  cn.x = sigm(gf.x) * cp.x + sigm(gi.x) * tanhf(gg.x); hn.x = sigm(go.x) * tanhf(cn.x);
  cn.y = sigm(gf.y) * cp.y + sigm(gi.y) * tanhf(gg.y); hn.y = sigm(go.y) * tanhf(cn.y);
  *(float2*)(out1 + base) = cn;
  *(float2*)(out0 + base) = hn;
}

// ---------------- keys GEMM, z-batched over 4 steps, quantized stores ----------------
__global__ __launch_bounds__(512) void keys_kernel(
    const float* __restrict__ hbase,
    const float* __restrict__ gW, const float* __restrict__ pW,
    const float* __restrict__ gB, const float* __restrict__ pB,
    ushort_t* gkh, uchar_t* gk8, ushort_t* gkn,
    ushort_t* pkh, uchar_t* pk8, ushort_t* pkn, int t0) {
  __shared__ float smem[64 * 68];
  float* As = smem;
  float* Bs = smem + 32 * 68;
  const int tid = threadIdx.x;
  const int tx = tid & 15, ty = tid >> 4;
  const int m0 = blockIdx.x * 64;
  const int nl = tid >> 3;
  const int c4 = (tid & 7) * 4;
  const int zz = blockIdx.z;
  const int t = t0 + zz;
  const float* A = hbase + (size_t)zz * NB * NH;

  const int j = blockIdx.y * 64 + nl;   // 0..511
  const float* brow = ((j < 256) ? (gW + (size_t)j * 256) : (pW + (size_t)(j - 256) * 256)) + c4;
  const float* ap = A + (size_t)(m0 + nl) * 256 + c4;

  GEMM_LOAD_COMPUTE()

  const int nbase = blockIdx.y * 64 + tx * 4;
  const bool isp = (nbase >= 256);
  const int n = isp ? (nbase - 256) : nbase;
  float4 b4 = *(const float4*)((isp ? pB : gB) + n);
  ushort_t* kh = isp ? pkh : gkh;
  uchar_t* k8 = isp ? pk8 : gk8;
  ushort_t* kn = isp ? pkn : gkn;
#pragma unroll
  for (int r = 0; r < 2; ++r) {
    int m = m0 + ty * 2 + r;
    float4 o;
    o.x = acc[r][0] + b4.x; o.y = acc[r][1] + b4.y;
    o.z = acc[r][2] + b4.z; o.w = acc[r][3] + b4.w;
    size_t row = (size_t)m * NS + t;
    ushort4 hi; uchar4 l8; ushort_t nib;
    pack28(o, hi, l8, nib);
    *(ushort4*)(kh + row * 256 + n) = hi;
    *(uchar4*)(k8 + row * 256 + n) = l8;
    kn[row * 64 + (n >> 2)] = nib;
  }
}

// ---------------- fused decoder attention: 4 batch rows / block, mask-skip ----------------
__global__ __launch_bounds__(1024, 1) void attn_kernel(
    const float* __restrict__ h, const float* __restrict__ gWT, const float* __restrict__ pWT,
    const float* __restrict__ gqb, const float* __restrict__ pqb,
    const ushort_t* __restrict__ gkh, const uchar_t* __restrict__ gk8, const ushort_t* __restrict__ gkn,
    const ushort_t* __restrict__ pkh, const uchar_t* __restrict__ pk8, const ushort_t* __restrict__ pkn,
    const float* __restrict__ gvw, const float* __restrict__ gvb,
    const float* __restrict__ pvw, const float* __restrict__ pvb,
    int* __restrict__ mask, const uint2* __restrict__ skeys, int t,
    float* __restrict__ out, int* __restrict__ chosen_buf) {
  __shared__ float hs[4][256], qs[4][256], vs[4][256], qq[4][256];
  __shared__ float part[4][4][256];
  __shared__ float wm[4][4], wl[4][4];
  __shared__ float lgs[4][NS], sv[4][NS];
  __shared__ int msk[4][NS];
  __shared__ float red_lse[4];
  __shared__ int ich[4];

  const int tid = threadIdx.x;
  const int grp = tid >> 8;          // 0..3 (4 whole waves each)
  const int gt = tid & 255;          // thread-in-group
  const int b = blockIdx.x * 4 + grp;
  const int wv = gt >> 6, lane = gt & 63;
  const int h0 = lane * 4;

  hs[grp][gt] = h[b * 256 + gt];
  vs[grp][gt] = gvw[gt];
  if (gt < NS) msk[grp][gt] = mask[b * NS + gt];
  __syncthreads();

  // ---- phase 1: qg = g_Wq . h + b ----
  {
    float a = gqb[gt];
    const float* wc = gWT + gt;
#pragma unroll 8
    for (int k = 0; k < 256; ++k) a = fmaf(wc[k * 256], hs[grp][k], a);
    qs[grp][gt] = a;
  }
  __syncthreads();

  // ---- phase 2: glimpse online-softmax attention (mask-skip: wave-uniform) ----
  {
    const float vbias = gvb[0];
    float q0 = qs[grp][h0], q1 = qs[grp][h0 + 1], q2 = qs[grp][h0 + 2], q3 = qs[grp][h0 + 3];
    float v0 = vs[grp][h0], v1 = vs[grp][h0 + 1], v2 = vs[grp][h0 + 2], v3 = vs[grp][h0 + 3];
    float m = -INFINITY, l = 0.f;
    float4 acc = make_float4(0.f, 0.f, 0.f, 0.f);
#pragma unroll 2
    for (int si = 0; si < 32; ++si) {
      int s = wv * 32 + si;
      if (msk[grp][s]) continue;   // same s across the whole wave -> no divergence
      size_t row = (size_t)b * NS + s;
      float4 kv = key_load(gkh, gk8, gkn, row, h0);
      float p = fast_tanh(q0 + kv.x) * v0 + fast_tanh(q1 + kv.y) * v1 +
                fast_tanh(q2 + kv.z) * v2 + fast_tanh(q3 + kv.w) * v3;
#pragma unroll
      for (int off = 32; off; off >>= 1) p += __shfl_xor(p, off);
      float lg = 10.0f * tanhf(p + vbias);
      float mn = fmaxf(m, lg);
      float scale = (m == -INFINITY) ? 0.0f : expf(m - mn);
      float pe = expf(lg - mn);
      acc.x = fmaf(acc.x, scale, pe * kv.x);
      acc.y = fmaf(acc.y, scale, pe * kv.y);
      acc.z = fmaf(acc.z, scale, pe * kv.z);
      acc.w = fmaf(acc.w, scale, pe * kv.w);
      l = l * scale + pe;
      m = mn;
    }
    *(float4*)&part[grp][wv][h0] = acc;
    if (lane == 0) { wm[grp][wv] = m; wl[grp][wv] = l; }
  }
  __syncthreads();
  {
    float mg = fmaxf(fmaxf(wm[grp][0], wm[grp][1]), fmaxf(wm[grp][2], wm[grp][3]));
    float w0 = (wm[grp][0] == -INFINITY) ? 0.f : expf(wm[grp][0] - mg);
    float w1 = (wm[grp][1] == -INFINITY) ? 0.f : expf(wm[grp][1] - mg);
    float w2 = (wm[grp][2] == -INFINITY) ? 0.f : expf(wm[grp][2] - mg);
    float w3 = (wm[grp][3] == -INFINITY) ? 0.f : expf(wm[grp][3] - mg);
    float denom = w0 * wl[grp][0] + w1 * wl[grp][1] + w2 * wl[grp][2] + w3 * wl[grp][3];
    float num = w0 * part[grp][0][gt] + w1 * part[grp][1][gt] +
                w2 * part[grp][2][gt] + w3 * part[grp][3][gt];
    qq[grp][gt] = num / denom;
    vs[grp][gt] = pvw[gt];
  }
  __syncthreads();

  // ---- phase 3: qp = p_Wq . query + b ----
  {
    float a = pqb[gt];
    const float* wc = pWT + gt;
#pragma unroll 8
    for (int k = 0; k < 256; ++k) a = fmaf(wc[k * 256], qq[grp][k], a);
    qs[grp][gt] = a;
  }
  __syncthreads();

  // ---- phase 4: pointer logits (mask-skip) ----
  {
    const float vbias = pvb[0];
    float q0 = qs[grp][h0], q1 = qs[grp][h0 + 1], q2 = qs[grp][h0 + 2], q3 = qs[grp][h0 + 3];
    float v0 = vs[grp][h0], v1 = vs[grp][h0 + 1], v2 = vs[grp][h0 + 2], v3 = vs[grp][h0 + 3];
#pragma unroll 2
    for (int si = 0; si < 32; ++si) {
      int s = wv * 32 + si;
      if (msk[grp][s]) {
        if (lane == 0) lgs[grp][s] = -100000.0f;
        continue;
      }
      size_t row = (size_t)b * NS + s;
      float4 kv = key_load(pkh, pk8, pkn, row, h0);
      float p = fast_tanh(q0 + kv.x) * v0 + fast_tanh(q1 + kv.y) * v1 +
                fast_tanh(q2 + kv.z) * v2 + fast_tanh(q3 + kv.w) * v3;
#pragma unroll
      for (int off = 32; off; off >>= 1) p += __shfl_down(p, off);
      if (lane == 0) lgs[grp][s] = 10.0f * tanhf(p + vbias);
    }
  }
  __syncthreads();
  if (wv == 0) {
    float a0 = lgs[grp][lane], a1 = lgs[grp][lane + 64];
    float m = fmaxf(a0, a1);
#pragma unroll
    for (int off = 32; off; off >>= 1) m = fmaxf(m, __shfl_xor(m, off));
    float e0 = expf(a0 - m), e1 = expf(a1 - m);
    float sum = e0 + e1;
#pragma unroll
    for (int off = 32; off; off >>= 1) sum += __shfl_xor(sum, off);
    if (lane == 0) red_lse[grp] = m + logf(sum);
  }
  __syncthreads();
  if (gt < NS) {
    uint32_t i = (uint32_t)(b * NS + gt);
    uint2 sk = skeys[t];
    uint32_t o0, o1;
    tf2x32(sk.x, sk.y, 0u, i, o0, o1);
    uint32_t bits = o0 ^ o1;
    float u = __uint_as_float((bits >> 9) | 0x3f800000u) - 1.0f;
    u = u + 1.17549435e-38f;
    u = fmaxf(u, 1.17549435e-38f);
    float g = -logf(-logf(u));
    sv[grp][gt] = lgs[grp][gt] + g;
  }
  __syncthreads();
  if (wv == 0) {
    float bv = sv[grp][lane]; int bi = lane;
    float ov0 = sv[grp][lane + 64];
    if (ov0 > bv) { bv = ov0; bi = lane + 64; }
#pragma unroll
    for (int off = 32; off; off >>= 1) {
      float ov = __shfl_down(bv, off);
      int oi = __shfl_down(bi, off);
      if (ov > bv) { bv = ov; bi = oi; }
    }
    if (lane == 0) ich[grp] = bi;
  }
  __syncthreads();
  if (gt == 0) {
    int cs = ich[grp];
    out[b * NS + t] = lgs[grp][cs] - red_lse[grp];
    out[NB * NS + b * NS + t] = (float)cs;
    mask[b * NS + cs] = 1;
    chosen_buf[b] = cs;
  }
}

extern "C" void kernel_launch(void* const* d_in, const int* in_sizes, int n_in,
                              void* d_out, int out_size, void* d_ws, size_t ws_size,
                              hipStream_t stream) {
  const float* x        = (const float*)d_in[0];
  const float* emb_W    = (const float*)d_in[1];
  const float* enc_W_ih = (const float*)d_in[2];
  const float* enc_W_hh = (const float*)d_in[3];
  const float* enc_b_ih = (const float*)d_in[4];
  const float* enc_b_hh = (const float*)d_in[5];
  const float* dec_W_ih = (const float*)d_in[6];
  const float* dec_W_hh = (const float*)d_in[7];
  const float* dec_b_ih = (const float*)d_in[8];
  const float* dec_b_hh = (const float*)d_in[9];
  const float* g_Wq_w = (const float*)d_in[10];
  const float* g_Wq_b = (const float*)d_in[11];
  const float* g_Wk_w = (const float*)d_in[12];
  const float* g_Wk_b = (const float*)d_in[13];
  const float* g_v_w  = (const float*)d_in[14];
  const float* g_v_b  = (const float*)d_in[15];
  const float* p_Wq_w = (const float*)d_in[16];
  const float* p_Wq_b = (const float*)d_in[17];
  const float* p_Wk_w = (const float*)d_in[18];
  const float* p_Wk_b = (const float*)d_in[19];
  const float* p_v_w  = (const float*)d_in[20];
  const float* p_v_b  = (const float*)d_in[21];
  const float* dec_start = (const float*)d_in[22];
  (void)in_sizes; (void)n_in;

  const size_t KELEM = (size_t)NB * NS * NH;   // 33.55M per head
  char* w = (char*)d_ws;
  size_t off = 0;
  auto alloc = [&](size_t bytes) -> void* {
    void* p = w + off;
    off += (bytes + 255) & ~(size_t)255;
    return p;
  };
  // quantized keys: 3.5 B/elem, both heads = 224 MiB total
  ushort_t* gkh = (ushort_t*)alloc(KELEM * 2);
  uchar_t*  gk8 = (uchar_t*)alloc(KELEM);
  ushort_t* gkn = (ushort_t*)alloc(KELEM / 2);
  ushort_t* pkh = (ushort_t*)alloc(KELEM * 2);
  uchar_t*  pk8 = (uchar_t*)alloc(KELEM);
  ushort_t* pkn = (ushort_t*)alloc(KELEM / 2);

  float* hb[4];
  for (int i = 0; i < 4; ++i) hb[i] = (float*)alloc((size_t)NB * NH * 4);
  float* cbuf   = (float*)alloc((size_t)NB * NH * 4);
  int*   mask   = (int*)alloc((size_t)NB * NS * 4);
  int*   chosen = (int*)alloc((size_t)NB * 4);
  float* F_enc  = (float*)alloc(2048 * 4);
  float* F_dec  = (float*)alloc(2048 * 4);
  float* d0proj = (float*)alloc(1024 * 4);
  uint2* skeys  = (uint2*)alloc(NS * 8);
  float* gWT    = (float*)alloc(256 * 256 * 4);
  float* pWT    = (float*)alloc(256 * 256 * 4);

  if (off > ws_size) {
    diag_fill<<<(out_size + 255) / 256, 256, 0, stream>>>((float*)d_out, (float)ws_size, out_size);
    return;
  }

  hipMemsetAsync(hb[3], 0, (size_t)NB * NH * 4, stream);   // zero h_in for encoder t=0
  hipMemsetAsync(cbuf, 0, (size_t)NB * NH * 4, stream);
  hipMemsetAsync(mask, 0, (size_t)NB * NS * 4, stream);
  prep_kernel<<<4, 256, 0, stream>>>(emb_W, enc_W_ih, dec_W_ih, dec_start,
                                     F_enc, F_dec, d0proj, skeys);
  transpose_qw<<<256, 256, 0, stream>>>(g_Wq_w, p_Wq_w, gWT, pWT);

  // ---- encoder: LSTM each step; keys batched every 4 steps ----
  for (int t = 0; t < NS; ++t) {
    const float* hin = (t == 0) ? hb[3] : hb[(t - 1) & 3];
    gemm_kernel<M_ENC><<<dim3(16, 16), 512, 0, stream>>>(
        hin, enc_W_hh, enc_b_ih, enc_b_hh, hb[t & 3], cbuf, x, F_enc, nullptr, t);
    if ((t & 3) == 3) {
      keys_kernel<<<dim3(16, 8, 4), 512, 0, stream>>>(
          hb[0], g_Wk_w, p_Wk_w, g_Wk_b, p_Wk_b,
          gkh, gk8, gkn, pkh, pk8, pkn, t - 3);
    }
  }
  // ---- decoder: LSTM + fused attention/sample per step ----
  for (int t = 0; t < NS; ++t) {
    const float* hin = (t == 0) ? hb[3] : hb[(t - 1) & 3];
    if (t == 0) {
      gemm_kernel<M_DEC0><<<dim3(16, 16), 512, 0, stream>>>(
          hin, dec_W_hh, dec_b_ih, dec_b_hh, hb[0], cbuf, nullptr, d0proj, nullptr, t);
    } else {
      gemm_kernel<M_DEC><<<dim3(16, 16), 512, 0, stream>>>(
          hin, dec_W_hh, dec_b_ih, dec_b_hh, hb[t & 3], cbuf, x, F_dec, chosen, t);
    }
    attn_kernel<<<NB / 4, 1024, 0, stream>>>(
        hb[t & 3], gWT, pWT, g_Wq_b, p_Wq_b,
        gkh, gk8, gkn, pkh, pk8, pkn,
        g_v_w, g_v_b, p_v_w, p_v_b, mask, skeys, t, (float*)d_out, chosen);
  }
}

// Round 8
// 13800.874 us; speedup vs baseline: 2.2390x; 1.0079x over previous
//
#include <hip/hip_runtime.h>
#include <cstdint>

#define NB 1024
#define NS 128
#define NH 256

typedef unsigned short ushort_t;
typedef unsigned char uchar_t;

__device__ __forceinline__ void tf2x32(uint32_t k0, uint32_t k1, uint32_t x0, uint32_t x1,
                                       uint32_t &o0, uint32_t &o1) {
  const uint32_t ks2 = k0 ^ k1 ^ 0x1BD11BDAu;
#define TF_R(r) { x0 += x1; x1 = (x1 << (r)) | (x1 >> (32 - (r))); x1 ^= x0; }
  x0 += k0; x1 += k1;
  TF_R(13) TF_R(15) TF_R(26) TF_R(6)
  x0 += k1; x1 += ks2 + 1u;
  TF_R(17) TF_R(29) TF_R(16) TF_R(24)
  x0 += ks2; x1 += k0 + 2u;
  TF_R(13) TF_R(15) TF_R(26) TF_R(6)
  x0 += k0; x1 += k1 + 3u;
  TF_R(17) TF_R(29) TF_R(16) TF_R(24)
  x0 += k1; x1 += ks2 + 4u;
  TF_R(13) TF_R(15) TF_R(26) TF_R(6)
  x0 += ks2; x1 += k0 + 5u;
#undef TF_R
  o0 = x0; o1 = x1;
}

__device__ __forceinline__ float fast_tanh(float x) {
  float ax = fabsf(x);
  float e = __expf(2.0f * ax);
  float r = 1.0f - 2.0f / (e + 1.0f);
  return copysignf(r, x);
}

__device__ __forceinline__ float sigm(float x) { return 1.0f / (1.0f + expf(-x)); }

// ---- 3.5-byte key codec: keep fp32 bits [31:4] with RTN. Arrays: hi16, lo8, nibble4 ----
__device__ __forceinline__ void pack28(float4 o, ushort4 &hi, uchar4 &l8, ushort_t &nib) {
  uint32_t a = __float_as_uint(o.x) + 8u;
  uint32_t b = __float_as_uint(o.y) + 8u;
  uint32_t c = __float_as_uint(o.z) + 8u;
  uint32_t d = __float_as_uint(o.w) + 8u;
  hi = make_ushort4((ushort_t)(a >> 16), (ushort_t)(b >> 16), (ushort_t)(c >> 16), (ushort_t)(d >> 16));
  l8 = make_uchar4((uchar_t)(a >> 8), (uchar_t)(b >> 8), (uchar_t)(c >> 8), (uchar_t)(d >> 8));
  nib = (ushort_t)(((a >> 4) & 0xFu) | (((b >> 4) & 0xFu) << 4) |
                   (((c >> 4) & 0xFu) << 8) | (((d >> 4) & 0xFu) << 12));
}

__device__ __forceinline__ float4 key_load(const ushort_t* __restrict__ kh,
                                           const uchar_t* __restrict__ k8,
                                           const ushort_t* __restrict__ kn,
                                           size_t row, int h0) {
  ushort4 hv = *(const ushort4*)(kh + row * 256 + h0);
  uchar4 lv = *(const uchar4*)(k8 + row * 256 + h0);
  uint32_t nv = kn[row * 64 + (h0 >> 2)];
  float4 r;
  r.x = __uint_as_float(((uint32_t)hv.x << 16) | ((uint32_t)lv.x << 8) | ((nv & 0xFu) << 4));
  r.y = __uint_as_float(((uint32_t)hv.y << 16) | ((uint32_t)lv.y << 8) | (((nv >> 4) & 0xFu) << 4));
  r.z = __uint_as_float(((uint32_t)hv.z << 16) | ((uint32_t)lv.z << 8) | (((nv >> 8) & 0xFu) << 4));
  r.w = __uint_as_float(((uint32_t)hv.w << 16) | ((uint32_t)lv.w << 8) | (((nv >> 12) & 0xFu) << 4));
  return r;
}

// ---------------- prep: fold emb_W through input weights; threefry split keys ----------------
__global__ __launch_bounds__(256) void prep_kernel(
    const float* __restrict__ emb_W, const float* __restrict__ enc_W_ih,
    const float* __restrict__ dec_W_ih, const float* __restrict__ dec_start,
    float* __restrict__ F_enc, float* __restrict__ F_dec,
    float* __restrict__ d0proj, uint2* __restrict__ skeys) {
  int j = blockIdx.x * 256 + threadIdx.x;  // 0..1023
  const float* er = enc_W_ih + j * 256;
  const float* dr = dec_W_ih + j * 256;
  float fe0 = 0.f, fe1 = 0.f, fd0 = 0.f, fd1 = 0.f, dp = 0.f;
  for (int e = 0; e < 256; ++e) {
    float we0 = emb_W[e], we1 = emb_W[256 + e];
    float ev = er[e], dv = dr[e];
    fe0 = fmaf(we0, ev, fe0); fe1 = fmaf(we1, ev, fe1);
    fd0 = fmaf(we0, dv, fd0); fd1 = fmaf(we1, dv, fd1);
    dp = fmaf(dec_start[e], dv, dp);
  }
  F_enc[j] = fe0; F_enc[1024 + j] = fe1;
  F_dec[j] = fd0; F_dec[1024 + j] = fd1;
  d0proj[j] = dp;
  if (blockIdx.x == 0 && threadIdx.x < NS) {
    uint32_t o0, o1;
    tf2x32(0u, 42u, 0u, (uint32_t)threadIdx.x, o0, o1);
    skeys[threadIdx.x] = make_uint2(o0, o1);
  }
}

// ---------------- transpose all weight matrices (k-major for coalesced matvec) ----------------
__global__ __launch_bounds__(1024) void transpose_all(
    const float* __restrict__ encW, const float* __restrict__ decW,
    const float* __restrict__ gWk, const float* __restrict__ pWk,
    const float* __restrict__ gWq, const float* __restrict__ pWq,
    float* __restrict__ encT, float* __restrict__ decT, float* __restrict__ WkT,
    float* __restrict__ gWT, float* __restrict__ pWT) {
  int k = blockIdx.x;        // 0..255
  int j = threadIdx.x;       // 0..1023
  encT[k * 1024 + j] = encW[j * 256 + k];
  decT[k * 1024 + j] = decW[j * 256 + k];
  if (j < 512) WkT[k * 512 + j] = (j < 256) ? gWk[j * 256 + k] : pWk[(j - 256) * 256 + k];
  if (j < 256) {
    gWT[k * 256 + j] = gWq[j * 256 + k];
    pWT[k * 256 + j] = pWq[j * 256 + k];
  }
}

__global__ void diag_fill(float* out, float v, int n) {
  int i = blockIdx.x * blockDim.x + threadIdx.x;
  if (i < n) out[i] = v;
}

// ---------------- the whole network: one plain kernel, 4 batch rows / block, no grid sync ----------------
__global__ __launch_bounds__(1024) void net_kernel(
    const float* __restrict__ x,
    const float* __restrict__ encT, const float* __restrict__ decT,
    const float* __restrict__ enc_b_ih, const float* __restrict__ enc_b_hh,
    const float* __restrict__ dec_b_ih, const float* __restrict__ dec_b_hh,
    const float* __restrict__ F_enc, const float* __restrict__ F_dec,
    const float* __restrict__ d0proj,
    const float* __restrict__ WkT, const float* __restrict__ gkb, const float* __restrict__ pkb,
    const float* __restrict__ gWT, const float* __restrict__ pWT,
    const float* __restrict__ gqb, const float* __restrict__ pqb,
    const float* __restrict__ gvw, const float* __restrict__ gvb,
    const float* __restrict__ pvw, const float* __restrict__ pvb,
    ushort_t* __restrict__ gkh, uchar_t* __restrict__ gk8, ushort_t* __restrict__ gkn,
    ushort_t* __restrict__ pkh, uchar_t* __restrict__ pk8, ushort_t* __restrict__ pkn,
    const uint2* __restrict__ skeys, float* __restrict__ out) {
  __shared__ float h4[256][4];        // h4[k][r]
  __shared__ float gx[1024][4];       // gate exchange [j][r]
  __shared__ float xs[1024];          // x preload [r][256]
  __shared__ float qs[4][256], vsm[4][256], qq[4][256];
  __shared__ float part[4][4][256];
  __shared__ float wm[4][4], wl[4][4];
  __shared__ float lgs[4][NS], sv[4][NS];
  __shared__ int msk[4][NS];
  __shared__ int chs[4];
  __shared__ float red_lse[4];
  __shared__ int ich[4];

  const int tid = threadIdx.x;
  const int r_own = tid >> 8, e_own = tid & 255;
  const int bb = blockIdx.x * 4;

  // preloads + init
  xs[tid] = x[(size_t)(bb + r_own) * 256 + e_own];
  if (tid < 512) ((int*)msk)[tid] = 0;
  ((float*)h4)[tid] = 0.0f;
  const float bse = enc_b_ih[tid] + enc_b_hh[tid];
  const float fae = F_enc[tid], fbe = F_enc[1024 + tid];
  const float bsd = dec_b_ih[tid] + dec_b_hh[tid];
  const float fad = F_dec[tid], fbd = F_dec[1024 + tid];
  const float d0p = d0proj[tid];
  float h_own = 0.0f, c_own = 0.0f;
  __syncthreads();

  // ================= encoder =================
  for (int t = 0; t < NS; ++t) {
    // LSTM matvec: thread j=tid computes gate j for all 4 rows
    float4 acc = make_float4(0.f, 0.f, 0.f, 0.f);
    {
      const float* wt = encT + tid;
      const float4* hv4 = (const float4*)h4;
#pragma unroll 8
      for (int k = 0; k < 256; ++k) {
        float4 hv = hv4[k];
        float w = wt[(size_t)k * 1024];
        acc.x = fmaf(w, hv.x, acc.x);
        acc.y = fmaf(w, hv.y, acc.y);
        acc.z = fmaf(w, hv.z, acc.z);
        acc.w = fmaf(w, hv.w, acc.w);
      }
    }
    {
      float4 v;
      v.x = acc.x + bse + xs[2 * t] * fae + xs[2 * t + 1] * fbe;
      v.y = acc.y + bse + xs[256 + 2 * t] * fae + xs[256 + 2 * t + 1] * fbe;
      v.z = acc.z + bse + xs[512 + 2 * t] * fae + xs[512 + 2 * t + 1] * fbe;
      v.w = acc.w + bse + xs[768 + 2 * t] * fae + xs[768 + 2 * t + 1] * fbe;
      *(float4*)gx[tid] = v;
    }
    __syncthreads();
    {
      float gi = gx[e_own][r_own], gf = gx[e_own + 256][r_own];
      float gg = gx[e_own + 512][r_own], go = gx[e_own + 768][r_own];
      c_own = sigm(gf) * c_own + sigm(gi) * tanhf(gg);
      h_own = sigm(go) * tanhf(c_own);
      h4[e_own][r_own] = h_own;
    }
    __syncthreads();
    // keys projection for step t (512 threads: row = tid>>7, 4 consecutive columns)
    if (tid < 512) {
      const int row = tid >> 7;
      const int j0 = (tid & 127) * 4;
      float4 ka = make_float4(0.f, 0.f, 0.f, 0.f);
#pragma unroll 8
      for (int k = 0; k < 256; ++k) {
        float hvs = h4[k][row];
        float4 w4 = *(const float4*)(WkT + (size_t)k * 512 + j0);
        ka.x = fmaf(hvs, w4.x, ka.x);
        ka.y = fmaf(hvs, w4.y, ka.y);
        ka.z = fmaf(hvs, w4.z, ka.z);
        ka.w = fmaf(hvs, w4.w, ka.w);
      }
      const bool isp = (j0 >= 256);
      const int n = isp ? (j0 - 256) : j0;
      float4 b4 = *(const float4*)((isp ? pkb : gkb) + n);
      ka.x += b4.x; ka.y += b4.y; ka.z += b4.z; ka.w += b4.w;
      size_t rowg = (size_t)(bb + row) * NS + t;
      ushort4 hi; uchar4 l8; ushort_t nib;
      pack28(ka, hi, l8, nib);
      ushort_t* kh = isp ? pkh : gkh;
      uchar_t* k8 = isp ? pk8 : gk8;
      ushort_t* kn = isp ? pkn : gkn;
      *(ushort4*)(kh + rowg * 256 + n) = hi;
      *(uchar4*)(k8 + rowg * 256 + n) = l8;
      kn[rowg * 64 + (n >> 2)] = nib;
    }
    __syncthreads();
  }

  // ================= decoder =================
  for (int t = 0; t < NS; ++t) {
    // LSTM matvec (dec weights)
    float4 acc = make_float4(0.f, 0.f, 0.f, 0.f);
    {
      const float* wt = decT + tid;
      const float4* hv4 = (const float4*)h4;
#pragma unroll 8
      for (int k = 0; k < 256; ++k) {
        float4 hv = hv4[k];
        float w = wt[(size_t)k * 1024];
        acc.x = fmaf(w, hv.x, acc.x);
        acc.y = fmaf(w, hv.y, acc.y);
        acc.z = fmaf(w, hv.z, acc.z);
        acc.w = fmaf(w, hv.w, acc.w);
      }
    }
    {
      float4 v;
      if (t == 0) {
        v.x = acc.x + bsd + d0p;
        v.y = acc.y + bsd + d0p;
        v.z = acc.z + bsd + d0p;
        v.w = acc.w + bsd + d0p;
      } else {
        int c0 = chs[0], c1 = chs[1], c2 = chs[2], c3 = chs[3];
        v.x = acc.x + bsd + xs[2 * c0] * fad + xs[2 * c0 + 1] * fbd;
        v.y = acc.y + bsd + xs[256 + 2 * c1] * fad + xs[256 + 2 * c1 + 1] * fbd;
        v.z = acc.z + bsd + xs[512 + 2 * c2] * fad + xs[512 + 2 * c2 + 1] * fbd;
        v.w = acc.w + bsd + xs[768 + 2 * c3] * fad + xs[768 + 2 * c3 + 1] * fbd;
      }
      *(float4*)gx[tid] = v;
    }
    __syncthreads();
    {
      float gi = gx[e_own][r_own], gf = gx[e_own + 256][r_own];
      float gg = gx[e_own + 512][r_own], go = gx[e_own + 768][r_own];
      c_own = sigm(gf) * c_own + sigm(gi) * tanhf(gg);
      h_own = sigm(go) * tanhf(c_own);
      h4[e_own][r_own] = h_own;
    }
    __syncthreads();

    // ---- fused attention + sample (round-7 body; hs -> h4, mask/chosen in LDS) ----
    {
      const int grp = tid >> 8;
      const int gt = tid & 255;
      const int b = bb + grp;
      const int wv = gt >> 6, lane = gt & 63;
      const int h0 = lane * 4;

      vsm[grp][gt] = gvw[gt];
      __syncthreads();

      // phase 1: qg = g_Wq . h + b
      {
        float a = gqb[gt];
        const float* wc = gWT + gt;
#pragma unroll 8
        for (int k = 0; k < 256; ++k) a = fmaf(wc[k * 256], h4[k][grp], a);
        qs[grp][gt] = a;
      }
      __syncthreads();

      // phase 2: glimpse online-softmax attention (mask-skip)
      {
        const float vbias = gvb[0];
        float q0 = qs[grp][h0], q1 = qs[grp][h0 + 1], q2 = qs[grp][h0 + 2], q3 = qs[grp][h0 + 3];
        float v0 = vsm[grp][h0], v1 = vsm[grp][h0 + 1], v2 = vsm[grp][h0 + 2], v3 = vsm[grp][h0 + 3];
        float m = -INFINITY, l = 0.f;
        float4 acc2 = make_float4(0.f, 0.f, 0.f, 0.f);
#pragma unroll 2
        for (int si = 0; si < 32; ++si) {
          int s = wv * 32 + si;
          if (msk[grp][s]) continue;
          size_t row = (size_t)b * NS + s;
          float4 kv = key_load(gkh, gk8, gkn, row, h0);
          float p = fast_tanh(q0 + kv.x) * v0 + fast_tanh(q1 + kv.y) * v1 +
                    fast_tanh(q2 + kv.z) * v2 + fast_tanh(q3 + kv.w) * v3;
#pragma unroll
          for (int off = 32; off; off >>= 1) p += __shfl_xor(p, off);
          float lg = 10.0f * tanhf(p + vbias);
          float mn = fmaxf(m, lg);
          float scale = (m == -INFINITY) ? 0.0f : expf(m - mn);
          float pe = expf(lg - mn);
          acc2.x = fmaf(acc2.x, scale, pe * kv.x);
          acc2.y = fmaf(acc2.y, scale, pe * kv.y);
          acc2.z = fmaf(acc2.z, scale, pe * kv.z);
          acc2.w = fmaf(acc2.w, scale, pe * kv.w);
          l = l * scale + pe;
          m = mn;
        }
        *(float4*)&part[grp][wv][h0] = acc2;
        if (lane == 0) { wm[grp][wv] = m; wl[grp][wv] = l; }
      }
      __syncthreads();
      {
        float mg = fmaxf(fmaxf(wm[grp][0], wm[grp][1]), fmaxf(wm[grp][2], wm[grp][3]));
        float w0 = (wm[grp][0] == -INFINITY) ? 0.f : expf(wm[grp][0] - mg);
        float w1 = (wm[grp][1] == -INFINITY) ? 0.f : expf(wm[grp][1] - mg);
        float w2 = (wm[grp][2] == -INFINITY) ? 0.f : expf(wm[grp][2] - mg);
        float w3 = (wm[grp][3] == -INFINITY) ? 0.f : expf(wm[grp][3] - mg);
        float denom = w0 * wl[grp][0] + w1 * wl[grp][1] + w2 * wl[grp][2] + w3 * wl[grp][3];
        float num = w0 * part[grp][0][gt] + w1 * part[grp][1][gt] +
                    w2 * part[grp][2][gt] + w3 * part[grp][3][gt];
        qq[grp][gt] = num / denom;
        vsm[grp][gt] = pvw[gt];
      }
      __syncthreads();

      // phase 3: qp = p_Wq . query + b
      {
        float a = pqb[gt];
        const float* wc = pWT + gt;
#pragma unroll 8
        for (int k = 0; k < 256; ++k) a = fmaf(wc[k * 256], qq[grp][k], a);
        qs[grp][gt] = a;
      }
      __syncthreads();

      // phase 4: pointer logits (mask-skip)
      {
        const float vbias = pvb[0];
        float q0 = qs[grp][h0], q1 = qs[grp][h0 + 1], q2 = qs[grp][h0 + 2], q3 = qs[grp][h0 + 3];
        float v0 = vsm[grp][h0], v1 = vsm[grp][h0 + 1], v2 = vsm[grp][h0 + 2], v3 = vsm[grp][h0 + 3];
#pragma unroll 2
        for (int si = 0; si < 32; ++si) {
          int s = wv * 32 + si;
          if (msk[grp][s]) {
            if (lane == 0) lgs[grp][s] = -100000.0f;
            continue;
          }
          size_t row = (size_t)b * NS + s;
          float4 kv = key_load(pkh, pk8, pkn, row, h0);
          float p = fast_tanh(q0 + kv.x) * v0 + fast_tanh(q1 + kv.y) * v1 +
                    fast_tanh(q2 + kv.z) * v2 + fast_tanh(q3 + kv.w) * v3;
#pragma unroll
          for (int off = 32; off; off >>= 1) p += __shfl_down(p, off);
          if (lane == 0) lgs[grp][s] = 10.0f * tanhf(p + vbias);
        }
      }
      __syncthreads();
      if (wv == 0) {
        float a0 = lgs[grp][lane], a1 = lgs[grp][lane + 64];
        float m = fmaxf(a0, a1);
#pragma unroll
        for (int off = 32; off; off >>= 1) m = fmaxf(m, __shfl_xor(m, off));
        float e0 = expf(a0 - m), e1 = expf(a1 - m);
        float sum = e0 + e1;
#pragma unroll
        for (int off = 32; off; off >>= 1) sum += __shfl_xor(sum, off);
        if (lane == 0) red_lse[grp] = m + logf(sum);
      }
      __syncthreads();
      if (gt < NS) {
        uint32_t i = (uint32_t)(b * NS + gt);
        uint2 sk = skeys[t];
        uint32_t o0, o1;
        tf2x32(sk.x, sk.y, 0u, i, o0, o1);
        uint32_t bits = o0 ^ o1;
        float u = __uint_as_float((bits >> 9) | 0x3f800000u) - 1.0f;
        u = u + 1.17549435e-38f;
        u = fmaxf(u, 1.17549435e-38f);
        float g = -logf(-logf(u));
        sv[grp][gt] = lgs[grp][gt] + g;
      }
      __syncthreads();
      if (wv == 0) {
        float bv = sv[grp][lane]; int bi = lane;
        float ov0 = sv[grp][lane + 64];
        if (ov0 > bv) { bv = ov0; bi = lane + 64; }
#pragma unroll
        for (int off = 32; off; off >>= 1) {
          float ov = __shfl_down(bv, off);
          int oi = __shfl_down(bi, off);
          if (ov > bv) { bv = ov; bi = oi; }
        }
        if (lane == 0) ich[grp] = bi;
      }
      __syncthreads();
      if (gt == 0) {
        int cs = ich[grp];
        out[(size_t)b * NS + t] = lgs[grp][cs] - red_lse[grp];
        out[(size_t)NB * NS + (size_t)b * NS + t] = (float)cs;
        msk[grp][cs] = 1;
        chs[grp] = cs;
      }
    }
    __syncthreads();
  }
}

extern "C" void kernel_launch(void* const* d_in, const int* in_sizes, int n_in,
                              void* d_out, int out_size, void* d_ws, size_t ws_size,
                              hipStream_t stream) {
  const float* x        = (const float*)d_in[0];
  const float* emb_W    = (const float*)d_in[1];
  const float* enc_W_ih = (const float*)d_in[2];
  const float* enc_W_hh = (const float*)d_in[3];
  const float* enc_b_ih = (const float*)d_in[4];
  const float* enc_b_hh = (const float*)d_in[5];
  const float* dec_W_ih = (const float*)d_in[6];
  const float* dec_W_hh = (const float*)d_in[7];
  const float* dec_b_ih = (const float*)d_in[8];
  const float* dec_b_hh = (const float*)d_in[9];
  const float* g_Wq_w = (const float*)d_in[10];
  const float* g_Wq_b = (const float*)d_in[11];
  const float* g_Wk_w = (const float*)d_in[12];
  const float* g_Wk_b = (const float*)d_in[13];
  const float* g_v_w  = (const float*)d_in[14];
  const float* g_v_b  = (const float*)d_in[15];
  const float* p_Wq_w = (const float*)d_in[16];
  const float* p_Wq_b = (const float*)d_in[17];
  const float* p_Wk_w = (const float*)d_in[18];
  const float* p_Wk_b = (const float*)d_in[19];
  const float* p_v_w  = (const float*)d_in[20];
  const float* p_v_b  = (const float*)d_in[21];
  const float* dec_start = (const float*)d_in[22];
  (void)in_sizes; (void)n_in;

  const size_t KELEM = (size_t)NB * NS * NH;   // 33.55M per head
  char* w = (char*)d_ws;
  size_t off = 0;
  auto alloc = [&](size_t bytes) -> void* {
    void* p = w + off;
    off += (bytes + 255) & ~(size_t)255;
    return p;
  };
  // quantized keys: 3.5 B/elem, both heads = 224 MiB total
  ushort_t* gkh = (ushort_t*)alloc(KELEM * 2);
  uchar_t*  gk8 = (uchar_t*)alloc(KELEM);
  ushort_t* gkn = (ushort_t*)alloc(KELEM / 2);
  ushort_t* pkh = (ushort_t*)alloc(KELEM * 2);
  uchar_t*  pk8 = (uchar_t*)alloc(KELEM);
  ushort_t* pkn = (ushort_t*)alloc(KELEM / 2);

  float* encT   = (float*)alloc(1024 * 256 * 4);
  float* decT   = (float*)alloc(1024 * 256 * 4);
  float* WkT    = (float*)alloc(512 * 256 * 4);
  float* gWT    = (float*)alloc(256 * 256 * 4);
  float* pWT    = (float*)alloc(256 * 256 * 4);
  float* F_enc  = (float*)alloc(2048 * 4);
  float* F_dec  = (float*)alloc(2048 * 4);
  float* d0proj = (float*)alloc(1024 * 4);
  uint2* skeys  = (uint2*)alloc(NS * 8);

  if (off > ws_size) {
    diag_fill<<<(out_size + 255) / 256, 256, 0, stream>>>((float*)d_out, (float)ws_size, out_size);
    return;
  }

  prep_kernel<<<4, 256, 0, stream>>>(emb_W, enc_W_ih, dec_W_ih, dec_start,
                                     F_enc, F_dec, d0proj, skeys);
  transpose_all<<<256, 1024, 0, stream>>>(enc_W_hh, dec_W_hh, g_Wk_w, p_Wk_w,
                                          g_Wq_w, p_Wq_w, encT, decT, WkT, gWT, pWT);
  net_kernel<<<NB / 4, 1024, 0, stream>>>(
      x, encT, decT, enc_b_ih, enc_b_hh, dec_b_ih, dec_b_hh,
      F_enc, F_dec, d0proj, WkT, g_Wk_b, p_Wk_b,
      gWT, pWT, g_Wq_b, p_Wq_b, g_v_w, g_v_b, p_v_w, p_v_b,
      gkh, gk8, gkn, pkh, pk8, pkn, skeys, (float*)d_out);
}